// Round 14
// baseline (51.255 us; speedup 1.0000x reference)
//
#include <hip/hip_runtime.h>
#include <hip/hip_bf16.h>

// BatchedNeRFMLP: B=64, N=16384, HID=128, POS_IN=63 (+bias col -> K=64), DIR_IN=27
// params per batch (TOTAL=8789 fp32):
//   pw [128][63] @0   pb[128]@8064   sw[128]@8192  sb@8320
//   cw [3][155] @8321 cb[3]@8786
// out: sigma (B*N) then rgb (B*N*3), fp32.
//
// r13 structure (47.6us best) + dir-tail folded into MFMA (front-append):
//   - head K extended 128 -> 160: s=8,9 carry cw[.][128+d] in natural k-order,
//     d==27 slot is 1.0 in B and sb/cb in A -> ALL biases ride the MFMA.
//   - hacc chains INITIALIZED with the 2 dir-MFMAs (2-deep, issued first);
//     L1's first repack lands later (4 serial MFMAs + VALU) -> critical path
//     unchanged, no extra accumulators (r9's end-append regressed; this won't).
//   - deletes the 110-instr scalar dir block; encode_dir costs ~45 -> net -65.
//   - 512 blocks x 8 iters: exactly 2 blocks/CU co-resident, zero tail  [r13]
//   - two 32-ray nt tiles interleaved (2 independent L1 MFMA chains)   [r11]
//   - haw in LDS (1.25KB, 10 s-slots)                                  [r7]
//   - encode(it+1) between frag-reads and MFMA (per-wave DS in-order)  [r5]
// r6-r10 lesson (3-for-3): (256,3+) spills -> pinned (256,2).
// Tripwire: WRITE_SIZE >> 16MB = spill = revert.
// Trig: v_sin/v_cos take REVOLUTIONS -> sin(pi x) = builtin_sinf(0.5x).

#define NB 64
#define NRAY 16384
#define NTOTAL 8789
#define NIT 8

typedef short bf16x8 __attribute__((ext_vector_type(8)));
typedef float f32x16 __attribute__((ext_vector_type(16)));

union U8 { unsigned u[4]; bf16x8 v; };

__device__ __forceinline__ unsigned pk2(float a, float b) {
    float2 t; t.x = a; t.y = b;
    __hip_bfloat162 h = __float22bfloat162_rn(t);   // v_cvt_pk_bf16_f32
    return *reinterpret_cast<unsigned*>(&h);
}

#define MFMA __builtin_amdgcn_mfma_f32_32x32x16_bf16

__global__ __launch_bounds__(256, 2) void nerf_mfma_kernel(
    const float* __restrict__ pos,
    const float* __restrict__ dir,
    const float* __restrict__ params,
    float* __restrict__ out)
{
    const int tid  = threadIdx.x;
    const int lane = tid & 63;
    const int wid  = tid >> 6;
    const int hi   = lane >> 5;
    const int l31  = lane & 31;

    const int b     = blockIdx.x >> 3;          // 8 blocks per batch
    const int chunk = (blockIdx.x & 7) << 11;   // 2048 rays per block
    const float* __restrict__ p = params + b * NTOTAL;

    __shared__ uint4 encs[2048];                // 256 rows x 128B (pos enc)
    __shared__ uint4 dirs[1024];                // 128 rows x 128B (2 rays/row)
    __shared__ unsigned hawLds[320];            // 10 s-slots x 128B = 1.25KB
    char* encb = reinterpret_cast<char*>(encs);
    char* dirb = reinterpret_cast<char*>(dirs);
    const char* hawb = reinterpret_cast<const char*>(hawLds);

    // ---- head-weight fragments into LDS (one-time) -------------------------
    // s=0..7 (hidden, K permuted): slot(s,hh,i) -> h=32*(s>>1)+16*(s&1)+4hh+(i&3)+8*(i>>2)
    if (tid < 64) {
        const int s  = tid & 7;
        const int hh = (tid >> 3) & 1;
        const int r  = tid >> 4;                // 0=sigma(sw), 1..3 = cw rows
        const float* w2 = (r == 0) ? (p + 8192) : (p + 8321 + (r - 1) * 155);
        const int base = 32 * (s >> 1) + 16 * (s & 1) + 4 * hh;
        unsigned* dst = &hawLds[(((s << 1) + hh) * 4 + r) * 4];
        #pragma unroll
        for (int j = 0; j < 4; ++j) {
            const int i0 = 2 * j, i1 = 2 * j + 1;
            dst[j] = pk2(w2[base + (i0 & 3) + 8 * (i0 >> 2)],
                         w2[base + (i1 & 3) + 8 * (i1 >> 2)]);
        }
    } else if (tid < 80) {
        // s=8,9 (dir part, NATURAL k-order); d==27 -> bias (sb/cb); d>27 -> 0
        const int t2 = tid - 64;
        const int s  = 8 + (t2 & 1);
        const int hh = (t2 >> 1) & 1;
        const int r  = t2 >> 2;
        const float* w2 = (r == 0) ? (p + 8192) : (p + 8321 + (r - 1) * 155);
        const float bias2 = (r == 0) ? p[8320] : p[8786 + r - 1];
        unsigned* dst = &hawLds[(((s << 1) + hh) * 4 + r) * 4];
        #pragma unroll
        for (int j = 0; j < 4; ++j) {
            const int d0 = (s - 8) * 16 + hh * 8 + 2 * j;
            const int d1 = d0 + 1;
            const float e0 = (d0 == 27) ? bias2 : ((d0 < 27 && r > 0) ? w2[128 + d0] : 0.f);
            const float e1 = (d1 == 27) ? bias2 : ((d1 < 27 && r > 0) ? w2[128 + d1] : 0.f);
            dst[j] = pk2(e0, e1);
        }
    }

    // ---- layer-1 A-frags, register-stationary ------------------------------
    // k<3 -> d=k ; k==3 -> pb[h] ; k>=4 -> d=k-1
    bf16x8 aw[4][4];
    #pragma unroll
    for (int mt = 0; mt < 4; ++mt) {
        const int hrow = mt * 32 + l31;
        const float* wrow = p + hrow * 63;
        const float bias = p[8064 + hrow];
        #pragma unroll
        for (int ks = 0; ks < 4; ++ks) {
            U8 u;
            #pragma unroll
            for (int j = 0; j < 4; ++j) {
                const int k0 = ks * 16 + hi * 8 + 2 * j;
                const int k1 = k0 + 1;
                const float e0 = (k0 < 3) ? wrow[k0] : (k0 == 3 ? bias : wrow[k0 - 1]);
                const float e1 = (k1 < 3) ? wrow[k1] : (k1 == 3 ? bias : wrow[k1 - 1]);
                u.u[j] = pk2(e0, e1);
            }
            aw[mt][ks] = u.v;
        }
    }

    f32x16 FZ;
    #pragma unroll
    for (int i = 0; i < 16; ++i) FZ[i] = 0.f;

    const int rayBlock = b * NRAY + chunk;
    float* __restrict__ rgbout = out + (long)NB * NRAY;
    const long pb0 = (long)(rayBlock + tid) * 3;
    const int hoff = hi * 64 + (l31 & 3) * 16;

    // ---- pos encoding into row `tid` (rolling 4-word buffer) ---------------
    auto encode_row = [&](const float3 Pv) {
        const int swz = (tid & 7) << 4;
        char* myrow = encb + tid * 128;
        float s0 = __builtin_amdgcn_sinf(0.5f * Pv.x), c0 = __builtin_amdgcn_cosf(0.5f * Pv.x);
        float s1 = __builtin_amdgcn_sinf(0.5f * Pv.y), c1 = __builtin_amdgcn_cosf(0.5f * Pv.y);
        float s2 = __builtin_amdgcn_sinf(0.5f * Pv.z), c2 = __builtin_amdgcn_cosf(0.5f * Pv.z);
        unsigned wb[4];
        wb[0] = pk2(Pv.x, Pv.y);
        wb[1] = pk2(Pv.z, 1.0f);
        #pragma unroll
        for (int f = 0; f < 10; ++f) {
            const int w = 2 + 3 * f;
            wb[(w + 0) & 3] = pk2(s0, s1);
            if (((w + 0) & 3) == 3) {
                uint4 v; v.x = wb[0]; v.y = wb[1]; v.z = wb[2]; v.w = wb[3];
                *reinterpret_cast<uint4*>(myrow + ((((w + 0) >> 2) * 16) ^ swz)) = v;
            }
            wb[(w + 1) & 3] = pk2(s2, c0);
            if (((w + 1) & 3) == 3) {
                uint4 v; v.x = wb[0]; v.y = wb[1]; v.z = wb[2]; v.w = wb[3];
                *reinterpret_cast<uint4*>(myrow + ((((w + 1) >> 2) * 16) ^ swz)) = v;
            }
            wb[(w + 2) & 3] = pk2(c1, c2);
            if (((w + 2) & 3) == 3) {
                uint4 v; v.x = wb[0]; v.y = wb[1]; v.z = wb[2]; v.w = wb[3];
                *reinterpret_cast<uint4*>(myrow + ((((w + 2) >> 2) * 16) ^ swz)) = v;
            }
            if (f < 9) {
                float t;
                t = 2.f * s0 * c0; c0 = fmaf(-2.f * s0, s0, 1.f); s0 = t;
                t = 2.f * s1 * c1; c1 = fmaf(-2.f * s1, s1, 1.f); s1 = t;
                t = 2.f * s2 * c2; c2 = fmaf(-2.f * s2, s2, 1.f); s2 = t;
            }
        }
    };

    // ---- dir encoding: 32 bf16 (27 + 1.0 + pad) into half-row tid>>1 -------
    auto encode_dir = [&](const float3 Dv) {
        const int row  = tid >> 1;
        const int half = tid & 1;
        const int dswz = (row & 7) << 4;
        char* base = dirb + row * 128;
        float s0 = __builtin_amdgcn_sinf(0.5f * Dv.x), c0 = __builtin_amdgcn_cosf(0.5f * Dv.x);
        float s1 = __builtin_amdgcn_sinf(0.5f * Dv.y), c1 = __builtin_amdgcn_cosf(0.5f * Dv.y);
        float s2 = __builtin_amdgcn_sinf(0.5f * Dv.z), c2 = __builtin_amdgcn_cosf(0.5f * Dv.z);
        unsigned wd[16];
        wd[0] = pk2(Dv.x, Dv.y);
        wd[1] = pk2(Dv.z, s0);
        wd[2] = pk2(s1, s2);
        wd[3] = pk2(c0, c1);
        #pragma unroll
        for (int f = 1; f < 4; ++f) {
            const float c2p = c2;
            float t;
            t = 2.f * s0 * c0; c0 = fmaf(-2.f * s0, s0, 1.f); s0 = t;
            t = 2.f * s1 * c1; c1 = fmaf(-2.f * s1, s1, 1.f); s1 = t;
            t = 2.f * s2 * c2; c2 = fmaf(-2.f * s2, s2, 1.f); s2 = t;
            wd[1 + 3 * f] = pk2(c2p, s0);
            wd[2 + 3 * f] = pk2(s1, s2);
            wd[3 + 3 * f] = pk2(c0, c1);
        }
        wd[13] = pk2(c2, 1.0f);   // d=27 slot = 1.0 -> multiplies bias in A
        wd[14] = 0u;
        wd[15] = 0u;
        #pragma unroll
        for (int c = 0; c < 4; ++c) {
            uint4 v;
            v.x = wd[4 * c + 0]; v.y = wd[4 * c + 1];
            v.z = wd[4 * c + 2]; v.w = wd[4 * c + 3];
            *reinterpret_cast<uint4*>(base + ((half * 64 + c * 16) ^ dswz)) = v;
        }
    };

    // prologue: prefetch inputs, encode iter-0
    float3 Pc = *reinterpret_cast<const float3*>(pos + pb0);
    float3 Pn = *reinterpret_cast<const float3*>(pos + pb0 + 768);
    float3 Dc = *reinterpret_cast<const float3*>(dir + pb0);
    float3 Dn = *reinterpret_cast<const float3*>(dir + pb0 + 768);
    encode_row(Pc);
    encode_dir(Dc);
    __syncthreads();    // hawLds ready (encs/dirs rows are wave-private)

    #pragma unroll 1
    for (int it = 0; it < NIT; ++it) {
        const int ray = rayBlock + it * 256 + tid;

        float3 Pn2, Dn2;
        if (it < NIT - 2) {
            Pn2 = *reinterpret_cast<const float3*>(pos + pb0 + (it + 2) * 768);
            Dn2 = *reinterpret_cast<const float3*>(dir + pb0 + (it + 2) * 768);
        }

        // ---- all frag reads first (rows hold enc/dir of iter it) -----------
        bf16x8 be0[4], be1[4], bd0[2], bd1[2];
        {
            const int row0 = wid * 64 + l31;
            const int swz0 = (row0 & 7) << 4;
            const int row1 = row0 + 32;
            const int swz1 = (row1 & 7) << 4;
            #pragma unroll
            for (int ks = 0; ks < 4; ++ks) {
                be0[ks] = *reinterpret_cast<const bf16x8*>(
                    encb + row0 * 128 + ((ks * 32 + hi * 16) ^ swz0));
                be1[ks] = *reinterpret_cast<const bf16x8*>(
                    encb + row1 * 128 + ((ks * 32 + hi * 16) ^ swz1));
            }
            const int dr0 = row0 >> 1, dh0 = row0 & 1, dsz0 = (dr0 & 7) << 4;
            const int dr1 = row1 >> 1, dh1 = row1 & 1, dsz1 = (dr1 & 7) << 4;
            #pragma unroll
            for (int t = 0; t < 2; ++t) {
                bd0[t] = *reinterpret_cast<const bf16x8*>(
                    dirb + dr0 * 128 + ((dh0 * 64 + t * 32 + hi * 16) ^ dsz0));
                bd1[t] = *reinterpret_cast<const bf16x8*>(
                    dirb + dr1 * 128 + ((dh1 * 64 + t * 32 + hi * 16) ^ dsz1));
            }
        }

        // ---- encode(it+1): writes after reads (per-wave DS in-order) -------
        if (it < NIT - 1) {
            encode_dir(Dn);
            encode_row(Pn);
        }

        // ---- MFMA region: dir chains (2-deep) init hacc, then L1+head ------
        __builtin_amdgcn_s_setprio(1);
        f32x16 hacc0, hacc1;
        {
            const bf16x8 hw8 = *reinterpret_cast<const bf16x8*>(hawb + 8 * 128 + hoff);
            const bf16x8 hw9 = *reinterpret_cast<const bf16x8*>(hawb + 9 * 128 + hoff);
            hacc0 = MFMA(hw8, bd0[0], FZ, 0, 0, 0);
            hacc1 = MFMA(hw8, bd1[0], FZ, 0, 0, 0);
            hacc0 = MFMA(hw9, bd0[1], hacc0, 0, 0, 0);
            hacc1 = MFMA(hw9, bd1[1], hacc1, 0, 0, 0);
        }
        #pragma unroll
        for (int mt = 0; mt < 4; ++mt) {
            f32x16 a0 = MFMA(aw[mt][0], be0[0], FZ, 0, 0, 0);
            f32x16 a1 = MFMA(aw[mt][0], be1[0], FZ, 0, 0, 0);
            a0 = MFMA(aw[mt][1], be0[1], a0, 0, 0, 0);
            a1 = MFMA(aw[mt][1], be1[1], a1, 0, 0, 0);
            a0 = MFMA(aw[mt][2], be0[2], a0, 0, 0, 0);
            a1 = MFMA(aw[mt][2], be1[2], a1, 0, 0, 0);
            a0 = MFMA(aw[mt][3], be0[3], a0, 0, 0, 0);
            a1 = MFMA(aw[mt][3], be1[3], a1, 0, 0, 0);

            // relu -> pack own regs (pi-permuted head K: no cross-lane moves)
            #pragma unroll
            for (int t = 0; t < 2; ++t) {
                const int rb = t * 8;
                const int s = 2 * mt + t;
                U8 u0, u1;
                #pragma unroll
                for (int j = 0; j < 4; ++j) {
                    u0.u[j] = pk2(fmaxf(a0[rb + 2 * j], 0.f),
                                  fmaxf(a0[rb + 2 * j + 1], 0.f));
                    u1.u[j] = pk2(fmaxf(a1[rb + 2 * j], 0.f),
                                  fmaxf(a1[rb + 2 * j + 1], 0.f));
                }
                const bf16x8 hw = *reinterpret_cast<const bf16x8*>(
                    hawb + s * 128 + hoff);
                hacc0 = MFMA(hw, u0.v, hacc0, 0, 0, 0);
                hacc1 = MFMA(hw, u1.v, hacc1, 0, 0, 0);
            }
        }
        __builtin_amdgcn_s_setprio(0);

        // ---- per-ray tail: select + sigmoid (biases already in hacc) -------
        const float sig = hi ? hacc1[0] : hacc0[0];
        float cr  = hi ? hacc1[1] : hacc0[1];
        float cg  = hi ? hacc1[2] : hacc0[2];
        float cbl = hi ? hacc1[3] : hacc0[3];

        cr  = 1.0f / (1.0f + __expf(-cr));
        cg  = 1.0f / (1.0f + __expf(-cg));
        cbl = 1.0f / (1.0f + __expf(-cbl));

        out[ray] = sig;
        float3 rgbv; rgbv.x = cr; rgbv.y = cg; rgbv.z = cbl;
        *reinterpret_cast<float3*>(rgbout + (long)ray * 3) = rgbv;

        Pn = Pn2; Dc = Dn; Dn = Dn2;
    }
}

extern "C" void kernel_launch(void* const* d_in, const int* in_sizes, int n_in,
                              void* d_out, int out_size, void* d_ws, size_t ws_size,
                              hipStream_t stream) {
    const float* pos    = (const float*)d_in[0];
    const float* dirs   = (const float*)d_in[1];
    const float* params = (const float*)d_in[2];
    float* out = (float*)d_out;

    dim3 grid(512);    // 8 blocks/batch x 64 batches; exactly 2 blocks/CU
    dim3 block(256);
    nerf_mfma_kernel<<<grid, block, 0, stream>>>(pos, dirs, params, out);
}

// Round 15
// 48.277 us; speedup vs baseline: 1.0617x; 1.0617x over previous
//
#include <hip/hip_runtime.h>
#include <hip/hip_bf16.h>

// BatchedNeRFMLP: B=64, N=16384, HID=128, POS_IN=63 (+bias col -> K=64), DIR_IN=27
// params per batch (TOTAL=8789 fp32):
//   pw [128][63] @0   pb[128]@8064   sw[128]@8192  sb@8320
//   cw [3][155] @8321 cb[3]@8786
// out: sigma (B*N) then rgb (B*N*3), fp32.
//
// r13 structure (47.6us best) + manual VALU/MFMA interleave:
//   The iteration's independent VALU (dir-tail dot, encode(it+1)) is CHUNKED
//   INTO the MFMA region, one chunk after each mt-step's 8 L1 MFMAs (those
//   have no VALU dependents until their repack). MFMA and VALU are separate
//   pipes; a wave can issue VALU in its own MFMAs' shadow. r14 lesson
//   (2nd confirmation): do NOT convert VALU to serial-chain MFMAs.
//     mt0 -> dir trig + 9 linear FMAs     mt1 -> dir 72-FMA dot
//     mt2 -> encode trig + freqs 0..4     mt3 -> encode freqs 5..9
//   - 512 blocks x 8 iters: exactly 2 blocks/CU co-resident, zero tail [r13]
//   - two 32-ray nt tiles interleaved (2 independent L1 MFMA chains)  [r11]
//   - haw in LDS (1KB)                                                [r7]
//   - encode writes after all frag reads (per-wave DS in-order)       [r5]
// r6-r10 lesson (3-for-3): (256,3+) spills -> pinned (256,2).
// Tripwire: WRITE_SIZE >> 16MB = spill = revert.
// Trig: v_sin/v_cos take REVOLUTIONS -> sin(pi x) = builtin_sinf(0.5x).

#define NB 64
#define NRAY 16384
#define NTOTAL 8789
#define NIT 8

typedef short bf16x8 __attribute__((ext_vector_type(8)));
typedef float f32x16 __attribute__((ext_vector_type(16)));

union U8 { unsigned u[4]; bf16x8 v; };

__device__ __forceinline__ unsigned pk2(float a, float b) {
    float2 t; t.x = a; t.y = b;
    __hip_bfloat162 h = __float22bfloat162_rn(t);   // v_cvt_pk_bf16_f32
    return *reinterpret_cast<unsigned*>(&h);
}

#define MFMA __builtin_amdgcn_mfma_f32_32x32x16_bf16

__global__ __launch_bounds__(256, 2) void nerf_mfma_kernel(
    const float* __restrict__ pos,
    const float* __restrict__ dir,
    const float* __restrict__ params,
    float* __restrict__ out)
{
    const int tid  = threadIdx.x;
    const int lane = tid & 63;
    const int wid  = tid >> 6;
    const int hi   = lane >> 5;
    const int l31  = lane & 31;

    const int b     = blockIdx.x >> 3;          // 8 blocks per batch
    const int chunk = (blockIdx.x & 7) << 11;   // 2048 rays per block
    const float* __restrict__ p = params + b * NTOTAL;

    __shared__ uint4 encs[2048];                // 256 rows x 128B, swizzled
    __shared__ unsigned hawLds[256];            // [s][hi][r][4 words] = 1KB
    char* encb = reinterpret_cast<char*>(encs);
    const char* hawb = reinterpret_cast<const char*>(hawLds);

    // ---- head-weight fragments into LDS (one-time, 64 threads) ------------
    // K permuted: slot(s,hh,i) -> h = 32*(s>>1)+16*(s&1)+4*hh+(i&3)+8*(i>>2)
    if (tid < 64) {
        const int s  = tid & 7;
        const int hh = (tid >> 3) & 1;
        const int r  = tid >> 4;                // 0=sigma(sw), 1..3 = cw rows
        const float* w2 = (r == 0) ? (p + 8192) : (p + 8321 + (r - 1) * 155);
        const int base = 32 * (s >> 1) + 16 * (s & 1) + 4 * hh;
        unsigned* dst = &hawLds[(((s << 1) + hh) * 4 + r) * 4];
        #pragma unroll
        for (int j = 0; j < 4; ++j) {
            const int i0 = 2 * j, i1 = 2 * j + 1;
            dst[j] = pk2(w2[base + (i0 & 3) + 8 * (i0 >> 2)],
                         w2[base + (i1 & 3) + 8 * (i1 >> 2)]);
        }
    }

    // ---- layer-1 A-frags, register-stationary ------------------------------
    // k<3 -> d=k ; k==3 -> pb[h] ; k>=4 -> d=k-1
    bf16x8 aw[4][4];
    #pragma unroll
    for (int mt = 0; mt < 4; ++mt) {
        const int hrow = mt * 32 + l31;
        const float* wrow = p + hrow * 63;
        const float bias = p[8064 + hrow];
        #pragma unroll
        for (int ks = 0; ks < 4; ++ks) {
            U8 u;
            #pragma unroll
            for (int j = 0; j < 4; ++j) {
                const int k0 = ks * 16 + hi * 8 + 2 * j;
                const int k1 = k0 + 1;
                const float e0 = (k0 < 3) ? wrow[k0] : (k0 == 3 ? bias : wrow[k0 - 1]);
                const float e1 = (k1 < 3) ? wrow[k1] : (k1 == 3 ? bias : wrow[k1 - 1]);
                u.u[j] = pk2(e0, e1);
            }
            aw[mt][ks] = u.v;
        }
    }

    f32x16 FZ;
    #pragma unroll
    for (int i = 0; i < 16; ++i) FZ[i] = 0.f;

    const float sb  = p[8320];
    const float cb0 = p[8786], cb1 = p[8787], cb2 = p[8788];
    const float* __restrict__ cwr  = p + 8321 + 128;
    const float* __restrict__ cwg  = p + 8321 + 155 + 128;
    const float* __restrict__ cwb2 = p + 8321 + 310 + 128;

    const int rayBlock = b * NRAY + chunk;
    float* __restrict__ rgbout = out + (long)NB * NRAY;
    const long pb0 = (long)(rayBlock + tid) * 3;
    const int hoff = hi * 64 + (l31 & 3) * 16;

    // ---- full pos encoding (prologue only; steady-state is chunked) --------
    auto encode_row = [&](const float3 Pv) {
        const int swz = (tid & 7) << 4;
        char* myrow = encb + tid * 128;
        float s0 = __builtin_amdgcn_sinf(0.5f * Pv.x), c0 = __builtin_amdgcn_cosf(0.5f * Pv.x);
        float s1 = __builtin_amdgcn_sinf(0.5f * Pv.y), c1 = __builtin_amdgcn_cosf(0.5f * Pv.y);
        float s2 = __builtin_amdgcn_sinf(0.5f * Pv.z), c2 = __builtin_amdgcn_cosf(0.5f * Pv.z);
        unsigned wb[4];
        wb[0] = pk2(Pv.x, Pv.y);
        wb[1] = pk2(Pv.z, 1.0f);
        #pragma unroll
        for (int f = 0; f < 10; ++f) {
            const int w = 2 + 3 * f;
            wb[(w + 0) & 3] = pk2(s0, s1);
            if (((w + 0) & 3) == 3) {
                uint4 v; v.x = wb[0]; v.y = wb[1]; v.z = wb[2]; v.w = wb[3];
                *reinterpret_cast<uint4*>(myrow + ((((w + 0) >> 2) * 16) ^ swz)) = v;
            }
            wb[(w + 1) & 3] = pk2(s2, c0);
            if (((w + 1) & 3) == 3) {
                uint4 v; v.x = wb[0]; v.y = wb[1]; v.z = wb[2]; v.w = wb[3];
                *reinterpret_cast<uint4*>(myrow + ((((w + 1) >> 2) * 16) ^ swz)) = v;
            }
            wb[(w + 2) & 3] = pk2(c1, c2);
            if (((w + 2) & 3) == 3) {
                uint4 v; v.x = wb[0]; v.y = wb[1]; v.z = wb[2]; v.w = wb[3];
                *reinterpret_cast<uint4*>(myrow + ((((w + 2) >> 2) * 16) ^ swz)) = v;
            }
            if (f < 9) {
                float t;
                t = 2.f * s0 * c0; c0 = fmaf(-2.f * s0, s0, 1.f); s0 = t;
                t = 2.f * s1 * c1; c1 = fmaf(-2.f * s1, s1, 1.f); s1 = t;
                t = 2.f * s2 * c2; c2 = fmaf(-2.f * s2, s2, 1.f); s2 = t;
            }
        }
    };

    // prologue: prefetch inputs, encode iter-0
    float3 Pc = *reinterpret_cast<const float3*>(pos + pb0);
    float3 Pn = *reinterpret_cast<const float3*>(pos + pb0 + 768);
    float3 Dc = *reinterpret_cast<const float3*>(dir + pb0);
    float3 Dn = *reinterpret_cast<const float3*>(dir + pb0 + 768);
    encode_row(Pc);
    __syncthreads();    // hawLds ready (encs rows are wave-private)

    #pragma unroll 1
    for (int it = 0; it < NIT; ++it) {
        const int ray = rayBlock + it * 256 + tid;

        float3 Pn2, Dn2;
        if (it < NIT - 2) {
            Pn2 = *reinterpret_cast<const float3*>(pos + pb0 + (it + 2) * 768);
            Dn2 = *reinterpret_cast<const float3*>(dir + pb0 + (it + 2) * 768);
        }

        // ---- all 8 B-frag reads first (rows hold enc(it)) ------------------
        bf16x8 be0[4], be1[4];
        {
            const int row0 = wid * 64 + l31;
            const int swz0 = (row0 & 7) << 4;
            const int row1 = row0 + 32;
            const int swz1 = (row1 & 7) << 4;
            #pragma unroll
            for (int ks = 0; ks < 4; ++ks) {
                be0[ks] = *reinterpret_cast<const bf16x8*>(
                    encb + row0 * 128 + ((ks * 32 + hi * 16) ^ swz0));
                be1[ks] = *reinterpret_cast<const bf16x8*>(
                    encb + row1 * 128 + ((ks * 32 + hi * 16) ^ swz1));
            }
        }

        // ---- interleaved region: MFMA chains + chunked independent VALU ----
        float d_s0, d_c0, d_s1, d_c1, d_s2, d_c2;       // dir trig state
        float crd = 0.f, cgd = 0.f, cbd = 0.f;          // dir dot accumulators
        float e_s0, e_c0, e_s1, e_c1, e_s2, e_c2;       // encode trig state
        unsigned ewb[4];                                 // rolling pack buffer

        __builtin_amdgcn_s_setprio(1);
        f32x16 hacc0, hacc1;
        #pragma unroll
        for (int mt = 0; mt < 4; ++mt) {
            f32x16 a0 = MFMA(aw[mt][0], be0[0], FZ, 0, 0, 0);
            f32x16 a1 = MFMA(aw[mt][0], be1[0], FZ, 0, 0, 0);
            a0 = MFMA(aw[mt][1], be0[1], a0, 0, 0, 0);
            a1 = MFMA(aw[mt][1], be1[1], a1, 0, 0, 0);
            a0 = MFMA(aw[mt][2], be0[2], a0, 0, 0, 0);
            a1 = MFMA(aw[mt][2], be1[2], a1, 0, 0, 0);
            a0 = MFMA(aw[mt][3], be0[3], a0, 0, 0, 0);
            a1 = MFMA(aw[mt][3], be1[3], a1, 0, 0, 0);

            // ---- independent VALU chunk in this mt's MFMA shadow -----------
            if (mt == 0) {          // dir trig + linear terms
                d_s0 = __builtin_amdgcn_sinf(0.5f * Dc.x); d_c0 = __builtin_amdgcn_cosf(0.5f * Dc.x);
                d_s1 = __builtin_amdgcn_sinf(0.5f * Dc.y); d_c1 = __builtin_amdgcn_cosf(0.5f * Dc.y);
                d_s2 = __builtin_amdgcn_sinf(0.5f * Dc.z); d_c2 = __builtin_amdgcn_cosf(0.5f * Dc.z);
                crd = fmaf(Dc.x, cwr[0], crd);  cgd = fmaf(Dc.x, cwg[0], cgd);  cbd = fmaf(Dc.x, cwb2[0], cbd);
                crd = fmaf(Dc.y, cwr[1], crd);  cgd = fmaf(Dc.y, cwg[1], cgd);  cbd = fmaf(Dc.y, cwb2[1], cbd);
                crd = fmaf(Dc.z, cwr[2], crd);  cgd = fmaf(Dc.z, cwg[2], cgd);  cbd = fmaf(Dc.z, cwb2[2], cbd);
            }
            if (mt == 1) {          // dir 72-FMA dot + doublings
                #pragma unroll
                for (int f = 0; f < 4; ++f) {
                    const int j = 3 + 6 * f;
                    crd = fmaf(d_s0, cwr[j+0], crd); cgd = fmaf(d_s0, cwg[j+0], cgd); cbd = fmaf(d_s0, cwb2[j+0], cbd);
                    crd = fmaf(d_s1, cwr[j+1], crd); cgd = fmaf(d_s1, cwg[j+1], cgd); cbd = fmaf(d_s1, cwb2[j+1], cbd);
                    crd = fmaf(d_s2, cwr[j+2], crd); cgd = fmaf(d_s2, cwg[j+2], cgd); cbd = fmaf(d_s2, cwb2[j+2], cbd);
                    crd = fmaf(d_c0, cwr[j+3], crd); cgd = fmaf(d_c0, cwg[j+3], cgd); cbd = fmaf(d_c0, cwb2[j+3], cbd);
                    crd = fmaf(d_c1, cwr[j+4], crd); cgd = fmaf(d_c1, cwg[j+4], cgd); cbd = fmaf(d_c1, cwb2[j+4], cbd);
                    crd = fmaf(d_c2, cwr[j+5], crd); cgd = fmaf(d_c2, cwg[j+5], cgd); cbd = fmaf(d_c2, cwb2[j+5], cbd);
                    if (f < 3) {
                        float t;
                        t = 2.f * d_s0 * d_c0; d_c0 = fmaf(-2.f * d_s0, d_s0, 1.f); d_s0 = t;
                        t = 2.f * d_s1 * d_c1; d_c1 = fmaf(-2.f * d_s1, d_s1, 1.f); d_s1 = t;
                        t = 2.f * d_s2 * d_c2; d_c2 = fmaf(-2.f * d_s2, d_s2, 1.f); d_s2 = t;
                    }
                }
            }
            if (mt == 2 && it < NIT - 1) {   // encode(it+1): trig + freqs 0..4
                e_s0 = __builtin_amdgcn_sinf(0.5f * Pn.x); e_c0 = __builtin_amdgcn_cosf(0.5f * Pn.x);
                e_s1 = __builtin_amdgcn_sinf(0.5f * Pn.y); e_c1 = __builtin_amdgcn_cosf(0.5f * Pn.y);
                e_s2 = __builtin_amdgcn_sinf(0.5f * Pn.z); e_c2 = __builtin_amdgcn_cosf(0.5f * Pn.z);
                const int swz = (tid & 7) << 4;
                char* myrow = encb + tid * 128;
                ewb[0] = pk2(Pn.x, Pn.y);
                ewb[1] = pk2(Pn.z, 1.0f);
                #pragma unroll
                for (int f = 0; f < 5; ++f) {
                    const int w = 2 + 3 * f;
                    ewb[(w + 0) & 3] = pk2(e_s0, e_s1);
                    if (((w + 0) & 3) == 3) {
                        uint4 v; v.x = ewb[0]; v.y = ewb[1]; v.z = ewb[2]; v.w = ewb[3];
                        *reinterpret_cast<uint4*>(myrow + ((((w + 0) >> 2) * 16) ^ swz)) = v;
                    }
                    ewb[(w + 1) & 3] = pk2(e_s2, e_c0);
                    if (((w + 1) & 3) == 3) {
                        uint4 v; v.x = ewb[0]; v.y = ewb[1]; v.z = ewb[2]; v.w = ewb[3];
                        *reinterpret_cast<uint4*>(myrow + ((((w + 1) >> 2) * 16) ^ swz)) = v;
                    }
                    ewb[(w + 2) & 3] = pk2(e_c1, e_c2);
                    if (((w + 2) & 3) == 3) {
                        uint4 v; v.x = ewb[0]; v.y = ewb[1]; v.z = ewb[2]; v.w = ewb[3];
                        *reinterpret_cast<uint4*>(myrow + ((((w + 2) >> 2) * 16) ^ swz)) = v;
                    }
                    float t;
                    t = 2.f * e_s0 * e_c0; e_c0 = fmaf(-2.f * e_s0, e_s0, 1.f); e_s0 = t;
                    t = 2.f * e_s1 * e_c1; e_c1 = fmaf(-2.f * e_s1, e_s1, 1.f); e_s1 = t;
                    t = 2.f * e_s2 * e_c2; e_c2 = fmaf(-2.f * e_s2, e_s2, 1.f); e_s2 = t;
                }
            }
            if (mt == 3 && it < NIT - 1) {   // encode(it+1): freqs 5..9
                const int swz = (tid & 7) << 4;
                char* myrow = encb + tid * 128;
                #pragma unroll
                for (int f = 5; f < 10; ++f) {
                    const int w = 2 + 3 * f;
                    ewb[(w + 0) & 3] = pk2(e_s0, e_s1);
                    if (((w + 0) & 3) == 3) {
                        uint4 v; v.x = ewb[0]; v.y = ewb[1]; v.z = ewb[2]; v.w = ewb[3];
                        *reinterpret_cast<uint4*>(myrow + ((((w + 0) >> 2) * 16) ^ swz)) = v;
                    }
                    ewb[(w + 1) & 3] = pk2(e_s2, e_c0);
                    if (((w + 1) & 3) == 3) {
                        uint4 v; v.x = ewb[0]; v.y = ewb[1]; v.z = ewb[2]; v.w = ewb[3];
                        *reinterpret_cast<uint4*>(myrow + ((((w + 1) >> 2) * 16) ^ swz)) = v;
                    }
                    ewb[(w + 2) & 3] = pk2(e_c1, e_c2);
                    if (((w + 2) & 3) == 3) {
                        uint4 v; v.x = ewb[0]; v.y = ewb[1]; v.z = ewb[2]; v.w = ewb[3];
                        *reinterpret_cast<uint4*>(myrow + ((((w + 2) >> 2) * 16) ^ swz)) = v;
                    }
                    if (f < 9) {
                        float t;
                        t = 2.f * e_s0 * e_c0; e_c0 = fmaf(-2.f * e_s0, e_s0, 1.f); e_s0 = t;
                        t = 2.f * e_s1 * e_c1; e_c1 = fmaf(-2.f * e_s1, e_s1, 1.f); e_s1 = t;
                        t = 2.f * e_s2 * e_c2; e_c2 = fmaf(-2.f * e_s2, e_s2, 1.f); e_s2 = t;
                    }
                }
            }

            // ---- relu -> pack own regs, head MFMAs (depends on a0/a1) ------
            #pragma unroll
            for (int t = 0; t < 2; ++t) {
                const int rb = t * 8;
                const int s = 2 * mt + t;
                U8 u0, u1;
                #pragma unroll
                for (int j = 0; j < 4; ++j) {
                    u0.u[j] = pk2(fmaxf(a0[rb + 2 * j], 0.f),
                                  fmaxf(a0[rb + 2 * j + 1], 0.f));
                    u1.u[j] = pk2(fmaxf(a1[rb + 2 * j], 0.f),
                                  fmaxf(a1[rb + 2 * j + 1], 0.f));
                }
                const bf16x8 hw = *reinterpret_cast<const bf16x8*>(
                    hawb + s * 128 + hoff);
                hacc0 = MFMA(hw, u0.v, (s == 0) ? FZ : hacc0, 0, 0, 0);
                hacc1 = MFMA(hw, u1.v, (s == 0) ? FZ : hacc1, 0, 0, 0);
            }
        }
        __builtin_amdgcn_s_setprio(0);

        // ---- per-ray tail: select + bias + dir partial + sigmoid -----------
        const float hv0 = hi ? hacc1[0] : hacc0[0];
        const float hv1 = hi ? hacc1[1] : hacc0[1];
        const float hv2 = hi ? hacc1[2] : hacc0[2];
        const float hv3 = hi ? hacc1[3] : hacc0[3];

        const float sig = hv0 + sb;
        float cr  = hv1 + cb0 + crd;
        float cg  = hv2 + cb1 + cgd;
        float cbl = hv3 + cb2 + cbd;

        cr  = 1.0f / (1.0f + __expf(-cr));
        cg  = 1.0f / (1.0f + __expf(-cg));
        cbl = 1.0f / (1.0f + __expf(-cbl));

        out[ray] = sig;
        float3 rgbv; rgbv.x = cr; rgbv.y = cg; rgbv.z = cbl;
        *reinterpret_cast<float3*>(rgbout + (long)ray * 3) = rgbv;

        Pn = Pn2; Dc = Dn; Dn = Dn2;
    }
}

extern "C" void kernel_launch(void* const* d_in, const int* in_sizes, int n_in,
                              void* d_out, int out_size, void* d_ws, size_t ws_size,
                              hipStream_t stream) {
    const float* pos    = (const float*)d_in[0];
    const float* dirs   = (const float*)d_in[1];
    const float* params = (const float*)d_in[2];
    float* out = (float*)d_out;

    dim3 grid(512);    // 8 blocks/batch x 64 batches; exactly 2 blocks/CU
    dim3 block(256);
    nerf_mfma_kernel<<<grid, block, 0, stream>>>(pos, dirs, params, out);
}

// Round 16
// 45.943 us; speedup vs baseline: 1.1156x; 1.0508x over previous
//
#include <hip/hip_runtime.h>
#include <hip/hip_bf16.h>

// BatchedNeRFMLP: B=64, N=16384, HID=128, POS_IN=63 (+bias col -> K=64), DIR_IN=27
// params per batch (TOTAL=8789 fp32):
//   pw [128][63] @0   pb[128]@8064   sw[128]@8192  sb@8320
//   cw [3][155] @8321 cb[3]@8786
// out: sigma (B*N) then rgb (B*N*3), fp32.
//
// Occupancy attempt #4 (r8/r10 causes addressed):
//   - aw -> LDS tile (16KB, pre-swizzled, shared by all waves)  -64 regs [r8]
//   - mt loop is #pragma unroll 1 with runtime mt: only awf0..3 (16 regs)
//     live at once; compiler CANNOT hoist awf reads across mt (r10's bug).
//   - hacc zero-init before mt loop (runtime mt forbids (s==0)?FZ: select).
//   - (256,3): arch ~= be32+awf16+repack8+prefetch9+temps15 ~ 80 <= 84;
//     acc = hacc32+a32+FZ16 = 80 <= 84. LDS 49KB x 3 = 147 <= 160KB.
//   - grid 1024 x 4 iters (768 resident + 256 tail).
// Carried r13 structure: two nt tiles interleaved [r11], haw in LDS [r7],
// encode(it+1) after all frag reads (per-wave DS in-order) [r5], dir-tail
// VALU before MFMA region [r11], revolution-trig [r9].
// Tripwire: WRITE_SIZE >> 16MB = spill = revert to r13 / (256,2) final.

#define NB 64
#define NRAY 16384
#define NTOTAL 8789
#define NIT 4

typedef short bf16x8 __attribute__((ext_vector_type(8)));
typedef float f32x16 __attribute__((ext_vector_type(16)));

union U8 { unsigned u[4]; bf16x8 v; };

__device__ __forceinline__ unsigned pk2(float a, float b) {
    float2 t; t.x = a; t.y = b;
    __hip_bfloat162 h = __float22bfloat162_rn(t);   // v_cvt_pk_bf16_f32
    return *reinterpret_cast<unsigned*>(&h);
}

#define MFMA __builtin_amdgcn_mfma_f32_32x32x16_bf16

__global__ __launch_bounds__(256, 3) void nerf_mfma_kernel(
    const float* __restrict__ pos,
    const float* __restrict__ dir,
    const float* __restrict__ params,
    float* __restrict__ out)
{
    const int tid  = threadIdx.x;
    const int lane = tid & 63;
    const int wid  = tid >> 6;
    const int hi   = lane >> 5;
    const int l31  = lane & 31;

    const int b     = blockIdx.x >> 4;          // 16 blocks per batch
    const int chunk = (blockIdx.x & 15) << 10;  // 1024 rays per block
    const float* __restrict__ p = params + b * NTOTAL;

    __shared__ uint4 encs[2048];                // 256 rows x 128B, swizzled
    __shared__ uint4 awT[1024];                 // 128 rows x 128B, swizzled
    __shared__ unsigned hawLds[256];            // [s][hi][r][4 words] = 1KB
    char* encb = reinterpret_cast<char*>(encs);
    const char* awb  = reinterpret_cast<const char*>(awT);
    const char* hawb = reinterpret_cast<const char*>(hawLds);

    // ---- head-weight fragments into LDS (one-time, 64 threads) ------------
    // K permuted: slot(s,hh,i) -> h = 32*(s>>1)+16*(s&1)+4*hh+(i&3)+8*(i>>2)
    if (tid < 64) {
        const int s  = tid & 7;
        const int hh = (tid >> 3) & 1;
        const int r  = tid >> 4;                // 0=sigma(sw), 1..3 = cw rows
        const float* w2 = (r == 0) ? (p + 8192) : (p + 8321 + (r - 1) * 155);
        const int base = 32 * (s >> 1) + 16 * (s & 1) + 4 * hh;
        unsigned* dst = &hawLds[(((s << 1) + hh) * 4 + r) * 4];
        #pragma unroll
        for (int j = 0; j < 4; ++j) {
            const int i0 = 2 * j, i1 = 2 * j + 1;
            dst[j] = pk2(w2[base + (i0 & 3) + 8 * (i0 >> 2)],
                         w2[base + (i1 & 3) + 8 * (i1 >> 2)]);
        }
    }

    // ---- layer-1 A tile into LDS (one-time, shared by all waves) ----------
    // K-order: k<3 -> pw[h][k]; k==3 -> pb[h]; k>=4 -> pw[h][k-1]
    {
        const int h    = tid >> 1;              // 0..127
        const int half = tid & 1;
        const float* wrow = p + h * 63;
        const float bias  = p[8064 + h];
        char* dst = reinterpret_cast<char*>(awT) + h * 128;
        const int swz = (h & 7) << 4;
        #pragma unroll
        for (int c4 = 0; c4 < 4; ++c4) {
            const int c = half * 4 + c4;
            U8 u;
            #pragma unroll
            for (int j = 0; j < 4; ++j) {
                const int k0 = 8 * c + 2 * j, k1 = k0 + 1;
                const float e0 = (k0 < 3) ? wrow[k0] : (k0 == 3 ? bias : wrow[k0 - 1]);
                const float e1 = (k1 < 3) ? wrow[k1] : (k1 == 3 ? bias : wrow[k1 - 1]);
                u.u[j] = pk2(e0, e1);
            }
            *reinterpret_cast<uint4*>(dst + ((c * 16) ^ swz)) =
                *reinterpret_cast<uint4*>(&u);
        }
    }

    f32x16 FZ;
    #pragma unroll
    for (int i = 0; i < 16; ++i) FZ[i] = 0.f;

    const float sb  = p[8320];
    const float cb0 = p[8786], cb1 = p[8787], cb2 = p[8788];
    const float* __restrict__ cwr  = p + 8321 + 128;
    const float* __restrict__ cwg  = p + 8321 + 155 + 128;
    const float* __restrict__ cwb2 = p + 8321 + 310 + 128;

    const int rayBlock = b * NRAY + chunk;
    float* __restrict__ rgbout = out + (long)NB * NRAY;
    const long pb0 = (long)(rayBlock + tid) * 3;
    const int hoff = hi * 64 + (l31 & 3) * 16;

    // ---- pos encoding into row `tid` (rolling 4-word buffer) ---------------
    auto encode_row = [&](const float3 Pv) {
        const int swz = (tid & 7) << 4;
        char* myrow = encb + tid * 128;
        float s0 = __builtin_amdgcn_sinf(0.5f * Pv.x), c0 = __builtin_amdgcn_cosf(0.5f * Pv.x);
        float s1 = __builtin_amdgcn_sinf(0.5f * Pv.y), c1 = __builtin_amdgcn_cosf(0.5f * Pv.y);
        float s2 = __builtin_amdgcn_sinf(0.5f * Pv.z), c2 = __builtin_amdgcn_cosf(0.5f * Pv.z);
        unsigned wb[4];
        wb[0] = pk2(Pv.x, Pv.y);
        wb[1] = pk2(Pv.z, 1.0f);
        #pragma unroll
        for (int f = 0; f < 10; ++f) {
            const int w = 2 + 3 * f;
            wb[(w + 0) & 3] = pk2(s0, s1);
            if (((w + 0) & 3) == 3) {
                uint4 v; v.x = wb[0]; v.y = wb[1]; v.z = wb[2]; v.w = wb[3];
                *reinterpret_cast<uint4*>(myrow + ((((w + 0) >> 2) * 16) ^ swz)) = v;
            }
            wb[(w + 1) & 3] = pk2(s2, c0);
            if (((w + 1) & 3) == 3) {
                uint4 v; v.x = wb[0]; v.y = wb[1]; v.z = wb[2]; v.w = wb[3];
                *reinterpret_cast<uint4*>(myrow + ((((w + 1) >> 2) * 16) ^ swz)) = v;
            }
            wb[(w + 2) & 3] = pk2(c1, c2);
            if (((w + 2) & 3) == 3) {
                uint4 v; v.x = wb[0]; v.y = wb[1]; v.z = wb[2]; v.w = wb[3];
                *reinterpret_cast<uint4*>(myrow + ((((w + 2) >> 2) * 16) ^ swz)) = v;
            }
            if (f < 9) {
                float t;
                t = 2.f * s0 * c0; c0 = fmaf(-2.f * s0, s0, 1.f); s0 = t;
                t = 2.f * s1 * c1; c1 = fmaf(-2.f * s1, s1, 1.f); s1 = t;
                t = 2.f * s2 * c2; c2 = fmaf(-2.f * s2, s2, 1.f); s2 = t;
            }
        }
    };

    // prologue: current inputs + iter-1 prefetch, encode iter-0
    float3 Pc = *reinterpret_cast<const float3*>(pos + pb0);
    float3 Dc = *reinterpret_cast<const float3*>(dir + pb0);
    encode_row(Pc);
    float3 Pn = *reinterpret_cast<const float3*>(pos + pb0 + 768);
    float3 Dn = *reinterpret_cast<const float3*>(dir + pb0 + 768);
    __syncthreads();    // awT + hawLds ready (encs rows are wave-private)

    #pragma unroll 1
    for (int it = 0; it < NIT; ++it) {
        const int ray = rayBlock + it * 256 + tid;

        // ---- all 8 B-frag reads first (rows hold enc(it)) ------------------
        bf16x8 be0[4], be1[4];
        {
            const int row0 = wid * 64 + l31;
            const int swz0 = (row0 & 7) << 4;
            const int row1 = row0 + 32;
            const int swz1 = (row1 & 7) << 4;
            #pragma unroll
            for (int ks = 0; ks < 4; ++ks) {
                be0[ks] = *reinterpret_cast<const bf16x8*>(
                    encb + row0 * 128 + ((ks * 32 + hi * 16) ^ swz0));
                be1[ks] = *reinterpret_cast<const bf16x8*>(
                    encb + row1 * 128 + ((ks * 32 + hi * 16) ^ swz1));
            }
        }

        // ---- encode(it+1): writes after reads (per-wave DS in-order) -------
        if (it < NIT - 1) encode_row(Pn);

        // ---- dir-tail partials: independent of MFMA -> latency filler ------
        float crd = 0.f, cgd = 0.f, cbd = 0.f;
        {
            float s0 = __builtin_amdgcn_sinf(0.5f * Dc.x), c0 = __builtin_amdgcn_cosf(0.5f * Dc.x);
            float s1 = __builtin_amdgcn_sinf(0.5f * Dc.y), c1 = __builtin_amdgcn_cosf(0.5f * Dc.y);
            float s2 = __builtin_amdgcn_sinf(0.5f * Dc.z), c2 = __builtin_amdgcn_cosf(0.5f * Dc.z);
            crd = fmaf(Dc.x, cwr[0], crd);  cgd = fmaf(Dc.x, cwg[0], cgd);  cbd = fmaf(Dc.x, cwb2[0], cbd);
            crd = fmaf(Dc.y, cwr[1], crd);  cgd = fmaf(Dc.y, cwg[1], cgd);  cbd = fmaf(Dc.y, cwb2[1], cbd);
            crd = fmaf(Dc.z, cwr[2], crd);  cgd = fmaf(Dc.z, cwg[2], cgd);  cbd = fmaf(Dc.z, cwb2[2], cbd);
            #pragma unroll
            for (int f = 0; f < 4; ++f) {
                const int j = 3 + 6 * f;
                crd = fmaf(s0, cwr[j+0], crd); cgd = fmaf(s0, cwg[j+0], cgd); cbd = fmaf(s0, cwb2[j+0], cbd);
                crd = fmaf(s1, cwr[j+1], crd); cgd = fmaf(s1, cwg[j+1], cgd); cbd = fmaf(s1, cwb2[j+1], cbd);
                crd = fmaf(s2, cwr[j+2], crd); cgd = fmaf(s2, cwg[j+2], cgd); cbd = fmaf(s2, cwb2[j+2], cbd);
                crd = fmaf(c0, cwr[j+3], crd); cgd = fmaf(c0, cwg[j+3], cgd); cbd = fmaf(c0, cwb2[j+3], cbd);
                crd = fmaf(c1, cwr[j+4], crd); cgd = fmaf(c1, cwg[j+4], cgd); cbd = fmaf(c1, cwb2[j+4], cbd);
                crd = fmaf(c2, cwr[j+5], crd); cgd = fmaf(c2, cwg[j+5], cgd); cbd = fmaf(c2, cwb2[j+5], cbd);
                if (f < 3) {
                    float t;
                    t = 2.f * s0 * c0; c0 = fmaf(-2.f * s0, s0, 1.f); s0 = t;
                    t = 2.f * s1 * c1; c1 = fmaf(-2.f * s1, s1, 1.f); s1 = t;
                    t = 2.f * s2 * c2; c2 = fmaf(-2.f * s2, s2, 1.f); s2 = t;
                }
            }
        }

        // ---- prefetch inputs for it+2 era (depth-1 rotate below) -----------
        float3 Pn2, Dn2;
        if (it < NIT - 2) {
            Pn2 = *reinterpret_cast<const float3*>(pos + pb0 + (it + 2) * 768);
            Dn2 = *reinterpret_cast<const float3*>(dir + pb0 + (it + 2) * 768);
        }

        // ---- MFMA region: mt loop NOT unrolled (awf stays 16 regs) ---------
        __builtin_amdgcn_s_setprio(1);
        f32x16 hacc0 = FZ, hacc1 = FZ;
        #pragma unroll 1
        for (int mt = 0; mt < 4; ++mt) {
            const int arow = (mt << 5) + l31;
            const int aswz = (arow & 7) << 4;
            const char* abase = awb + arow * 128;
            const bf16x8 awf0 = *reinterpret_cast<const bf16x8*>(abase + ((0  + hi * 16) ^ aswz));
            const bf16x8 awf1 = *reinterpret_cast<const bf16x8*>(abase + ((32 + hi * 16) ^ aswz));
            const bf16x8 awf2 = *reinterpret_cast<const bf16x8*>(abase + ((64 + hi * 16) ^ aswz));
            const bf16x8 awf3 = *reinterpret_cast<const bf16x8*>(abase + ((96 + hi * 16) ^ aswz));

            f32x16 a0 = MFMA(awf0, be0[0], FZ, 0, 0, 0);
            f32x16 a1 = MFMA(awf0, be1[0], FZ, 0, 0, 0);
            a0 = MFMA(awf1, be0[1], a0, 0, 0, 0);
            a1 = MFMA(awf1, be1[1], a1, 0, 0, 0);
            a0 = MFMA(awf2, be0[2], a0, 0, 0, 0);
            a1 = MFMA(awf2, be1[2], a1, 0, 0, 0);
            a0 = MFMA(awf3, be0[3], a0, 0, 0, 0);
            a1 = MFMA(awf3, be1[3], a1, 0, 0, 0);

            // relu -> pack own regs (pi-permuted head K: no cross-lane moves)
            #pragma unroll
            for (int t = 0; t < 2; ++t) {
                const int rb = t * 8;
                U8 u0, u1;
                #pragma unroll
                for (int j = 0; j < 4; ++j) {
                    u0.u[j] = pk2(fmaxf(a0[rb + 2 * j], 0.f),
                                  fmaxf(a0[rb + 2 * j + 1], 0.f));
                    u1.u[j] = pk2(fmaxf(a1[rb + 2 * j], 0.f),
                                  fmaxf(a1[rb + 2 * j + 1], 0.f));
                }
                const bf16x8 hw = *reinterpret_cast<const bf16x8*>(
                    hawb + (2 * mt + t) * 128 + hoff);
                hacc0 = MFMA(hw, u0.v, hacc0, 0, 0, 0);
                hacc1 = MFMA(hw, u1.v, hacc1, 0, 0, 0);
            }
        }
        __builtin_amdgcn_s_setprio(0);

        // ---- per-ray tail: select + bias + dir partial + sigmoid -----------
        const float hv0 = hi ? hacc1[0] : hacc0[0];
        const float hv1 = hi ? hacc1[1] : hacc0[1];
        const float hv2 = hi ? hacc1[2] : hacc0[2];
        const float hv3 = hi ? hacc1[3] : hacc0[3];

        const float sig = hv0 + sb;
        float cr  = hv1 + cb0 + crd;
        float cg  = hv2 + cb1 + cgd;
        float cbl = hv3 + cb2 + cbd;

        cr  = 1.0f / (1.0f + __expf(-cr));
        cg  = 1.0f / (1.0f + __expf(-cg));
        cbl = 1.0f / (1.0f + __expf(-cbl));

        out[ray] = sig;
        float3 rgbv; rgbv.x = cr; rgbv.y = cg; rgbv.z = cbl;
        *reinterpret_cast<float3*>(rgbout + (long)ray * 3) = rgbv;

        Pn = Pn2; Dc = Dn; Dn = Dn2;
    }
}

extern "C" void kernel_launch(void* const* d_in, const int* in_sizes, int n_in,
                              void* d_out, int out_size, void* d_ws, size_t ws_size,
                              hipStream_t stream) {
    const float* pos    = (const float*)d_in[0];
    const float* dirs   = (const float*)d_in[1];
    const float* params = (const float*)d_in[2];
    float* out = (float*)d_out;

    dim3 grid(1024);   // 16 blocks/batch x 64 batches, 1024 rays each
    dim3 block(256);
    nerf_mfma_kernel<<<grid, block, 0, stream>>>(pos, dirs, params, out);
}